// Round 4
// baseline (277.768 us; speedup 1.0000x reference)
//
#include <hip/hip_runtime.h>

// Problem constants (fixed by setup_inputs)
#define NB   8      // batch
#define NN   1024   // nodes
#define DIN  256
#define DOUT 256
#define NH   8      // heads
#define DH   32     // head dim
constexpr float LN_EPS   = 1e-5f;
constexpr float QK_SCALE = 0.17677669529663687f; // 1/sqrt(32)

typedef __attribute__((ext_vector_type(8))) short s16x8;   // 8 bf16 (4 VGPR)
typedef __attribute__((ext_vector_type(4))) float f32x4;   // MFMA acc

__device__ __forceinline__ unsigned short f2bf(float f) {  // RNE fp32->bf16
    unsigned int u = __float_as_uint(f);
    u += 0x7FFFu + ((u >> 16) & 1u);
    return (unsigned short)(u >> 16);
}
__device__ __forceinline__ float bf2f(unsigned short h) {
    return __uint_as_float(((unsigned int)h) << 16);
}
__device__ __forceinline__ unsigned int packbf(float a, float b) {
    return (unsigned int)f2bf(a) | ((unsigned int)f2bf(b) << 16);
}

// ---------------------------------------------------------------------------
// Kernel 1: weight convert.  W (256x256, [k][n] fp32) -> Wt [n][k] bf16 hi/lo.
// Per matrix: hi block 65536 shorts, then lo block 65536.  4 matrices.
// (verbatim from round 3 -- proven)
// ---------------------------------------------------------------------------
__global__ __launch_bounds__(256) void wsplit_kernel(
    const float* __restrict__ W0, const float* __restrict__ W1,
    const float* __restrict__ W2, const float* __restrict__ W3,
    unsigned short* __restrict__ Wt)
{
    const int mat = blockIdx.z;
    const int k0 = blockIdx.x * 64, n0 = blockIdx.y * 64;
    const float* W = (mat==0)?W0:(mat==1)?W1:(mat==2)?W2:W3;
    __shared__ float T[64][65];
    const int t = threadIdx.x;
    {
        const int r = t >> 2, cs = (t & 3) * 16;
        const float* src = W + (k0 + r)*256 + n0 + cs;
#pragma unroll
        for (int i = 0; i < 4; ++i) {
            float4 v = *(const float4*)(src + i*4);
            T[r][cs+i*4+0] = v.x; T[r][cs+i*4+1] = v.y;
            T[r][cs+i*4+2] = v.z; T[r][cs+i*4+3] = v.w;
        }
    }
    __syncthreads();
    {
        const int nr = t >> 2, ks = (t & 3) * 16;
        unsigned short hbuf[16], lbuf[16];
#pragma unroll
        for (int i = 0; i < 16; ++i) {
            float x = T[ks + i][nr];
            unsigned short hb = f2bf(x);
            hbuf[i] = hb;
            lbuf[i] = f2bf(x - bf2f(hb));
        }
        unsigned short* dh = Wt + mat*131072 + (n0+nr)*256 + k0 + ks;
        *(s16x8*)dh           = *(const s16x8*)hbuf;
        *(s16x8*)(dh+8)       = *(const s16x8*)(hbuf+8);
        *(s16x8*)(dh+65536)   = *(const s16x8*)lbuf;
        *(s16x8*)(dh+65536+8) = *(const s16x8*)(lbuf+8);
    }
}

// ---------------------------------------------------------------------------
// Kernel 2: QKV projection via MFMA, LDS-staged, XOR-swizzled, prefetched.
// Block = 64 feats (all 3 mats) x 64 nodes.  Wave w: feats w*16, all 64 nodes.
// X converted fp32->bf16 hi/lo during staging (no xsplit kernel).
// ---------------------------------------------------------------------------
__global__ __launch_bounds__(256) void qkv_kernel(
    const float* __restrict__ X, const unsigned short* __restrict__ Wt,
    const float* __restrict__ bq, const float* __restrict__ bk, const float* __restrict__ bv,
    unsigned short* __restrict__ Qh, unsigned short* __restrict__ Ql,
    unsigned short* __restrict__ Kb, unsigned short* __restrict__ Vt)
{
    const int N0 = blockIdx.x * 64;
    const int F0 = blockIdx.y * 64;
    const int t = threadIdx.x, lane = t & 63, wid = t >> 6;
    const int l15 = lane & 15, hi = lane >> 4, hi4 = hi * 4;

    __shared__ unsigned short Xall[2*64*4*8];   // [hl][node][kchunk] 16B blocks, swizzled
    __shared__ unsigned short Wall[2*192*4*8];  // [hl*192+mat*64+feat][kchunk]

    // --- staging maps ---
    const int xn = t >> 2, xseg = t & 3;
    const size_t xsrc = (size_t)(N0 + xn)*256 + xseg*8;
    const int xsw = xseg ^ ((xn >> 3) & 3);
    const int xdst_h = (xn*4 + xsw) * 8;
    const int xdst_l = ((64 + xn)*4 + xsw) * 8;

    int wdst[6]; size_t wsrc[6];
#pragma unroll
    for (int i = 0; i < 6; ++i) {
        const int c = t + 256*i, row = c >> 2, kgrp = c & 3;
        const int hl = (row >= 192) ? 1 : 0, rr = row - hl*192;
        const int mat = rr >> 6, feat = rr & 63;
        wsrc[i] = (size_t)mat*131072 + (size_t)hl*65536 + (size_t)(F0 + feat)*256 + kgrp*8;
        wdst[i] = (row*4 + (kgrp ^ ((feat >> 3) & 3))) * 8;
    }

    // --- fragment read addresses ---
    const int wfeat = wid*16 + l15;
    const int axor = hi ^ ((wfeat >> 3) & 3);
    int aaddr[3][2], baddr[4][2];
#pragma unroll
    for (int m = 0; m < 3; ++m) {
        aaddr[m][0] = ((m*64 + wfeat)*4 + axor) * 8;
        aaddr[m][1] = ((192 + m*64 + wfeat)*4 + axor) * 8;
    }
#pragma unroll
    for (int c = 0; c < 4; ++c) {
        const int node = c*16 + l15;
        const int bx = hi ^ ((node >> 3) & 3);
        baddr[c][0] = (node*4 + bx) * 8;
        baddr[c][1] = ((64 + node)*4 + bx) * 8;
    }

    f32x4 acc[3][4];
#pragma unroll
    for (int m = 0; m < 3; ++m)
#pragma unroll
        for (int c = 0; c < 4; ++c) acc[m][c] = (f32x4){0.f,0.f,0.f,0.f};

    // --- prefetch regs ---
    float4 xr0, xr1; uint4 wr[6];
    xr0 = *(const float4*)(X + xsrc);
    xr1 = *(const float4*)(X + xsrc + 4);
#pragma unroll
    for (int i = 0; i < 6; ++i) wr[i] = *(const uint4*)(Wt + wsrc[i]);

    for (int ks = 0; ks < 8; ++ks) {
        __syncthreads();
        {   // write staged tile (convert X)
            const float v[8] = {xr0.x, xr0.y, xr0.z, xr0.w, xr1.x, xr1.y, xr1.z, xr1.w};
            unsigned short h8[8], l8[8];
#pragma unroll
            for (int j = 0; j < 8; ++j) {
                h8[j] = f2bf(v[j]);
                l8[j] = f2bf(v[j] - bf2f(h8[j]));
            }
            *(s16x8*)&Xall[xdst_h] = *(const s16x8*)h8;
            *(s16x8*)&Xall[xdst_l] = *(const s16x8*)l8;
#pragma unroll
            for (int i = 0; i < 6; ++i) *(uint4*)&Wall[wdst[i]] = wr[i];
        }
        __syncthreads();
        if (ks < 7) {   // prefetch next k-tile (overlaps MFMA below)
            const int k0 = (ks + 1) * 32;
            xr0 = *(const float4*)(X + xsrc + k0);
            xr1 = *(const float4*)(X + xsrc + k0 + 4);
#pragma unroll
            for (int i = 0; i < 6; ++i) wr[i] = *(const uint4*)(Wt + wsrc[i] + k0);
        }
        // compute
        s16x8 ah[3], al[3];
#pragma unroll
        for (int m = 0; m < 3; ++m) {
            ah[m] = *(const s16x8*)&Wall[aaddr[m][0]];
            al[m] = *(const s16x8*)&Wall[aaddr[m][1]];
        }
#pragma unroll
        for (int c = 0; c < 4; ++c) {
            const s16x8 bh = *(const s16x8*)&Xall[baddr[c][0]];
            const s16x8 bl = *(const s16x8*)&Xall[baddr[c][1]];
#pragma unroll
            for (int m = 0; m < 3; ++m) {
                acc[m][c] = __builtin_amdgcn_mfma_f32_16x16x32_bf16(ah[m], bh, acc[m][c], 0,0,0);
                acc[m][c] = __builtin_amdgcn_mfma_f32_16x16x32_bf16(al[m], bh, acc[m][c], 0,0,0);
                acc[m][c] = __builtin_amdgcn_mfma_f32_16x16x32_bf16(ah[m], bl, acc[m][c], 0,0,0);
            }
        }
    }

    // --- epilogue (write layouts proven in round 3) ---
    const int f0 = F0 + wid*16 + hi4;           // 4 consecutive feats, no head cross
    const int hh = f0 >> 5, d0 = f0 & 31;
#pragma unroll
    for (int m = 0; m < 3; ++m) {
        const float* bias = (m==0) ? bq : (m==1) ? bk : bv;
        const float4 bs4 = *(const float4*)&bias[f0];
        const float bsa[4] = {bs4.x, bs4.y, bs4.z, bs4.w};
#pragma unroll
        for (int c = 0; c < 4; ++c) {
            const int g = N0 + c*16 + l15;
            const int b = g >> 10, nn = g & (NN - 1);
            const size_t base = ((size_t)(b*NH + hh)*NN + nn)*DH + d0;
            if (m == 0) {
                ushort4 qh4, ql4;
#pragma unroll
                for (int r = 0; r < 4; ++r) {
                    const float q = (acc[0][c][r] + bsa[r]) * QK_SCALE;
                    const unsigned short hb = f2bf(q);
                    ((unsigned short*)&qh4)[r] = hb;
                    ((unsigned short*)&ql4)[r] = f2bf(q - bf2f(hb));
                }
                *(ushort4*)&Qh[base] = qh4;
                *(ushort4*)&Ql[base] = ql4;
            } else if (m == 1) {
                ushort4 kb4;
#pragma unroll
                for (int r = 0; r < 4; ++r)
                    ((unsigned short*)&kb4)[r] = f2bf(acc[1][c][r] + bsa[r]);
                *(ushort4*)&Kb[base] = kb4;
            } else {
#pragma unroll
                for (int r = 0; r < 4; ++r)
                    Vt[((size_t)(b*NH + hh)*DH + d0 + r)*NN + nn] =
                        f2bf(acc[2][c][r] + bsa[r]);
            }
        }
    }
}

// ---------------------------------------------------------------------------
// Kernel 3: flash attention.  LDS-staged K/V/E (swizzled), P in registers via
// sigma key-permutation (proven round 3), async-split prefetch, defer-max.
// Block = (b, h, 64-q tile), 4 waves.  b = bid&7 pins E slice per XCD L2.
// ---------------------------------------------------------------------------
__global__ __launch_bounds__(256) void attn_kernel(
    const unsigned short* __restrict__ Qh, const unsigned short* __restrict__ Ql,
    const unsigned short* __restrict__ Kb, const unsigned short* __restrict__ Vt,
    const float* __restrict__ Eg, const float* __restrict__ We,
    unsigned short* __restrict__ AOh, unsigned short* __restrict__ AOl)
{
    const int bid = blockIdx.x;
    const int b = bid & 7, h = (bid >> 3) & 7, qt = bid >> 6;
    const int q0 = qt * 64;
    const int t = threadIdx.x, lane = t & 63, wid = t >> 6;
    const int l15 = lane & 15, hi = lane >> 4, hi4 = hi * 4;

    __shared__ unsigned short Ks[64*4*8];   // [key][kchunk] swizzled, 4 KB
    __shared__ unsigned short Vs[8*32*8];   // [kg][dh] swizzled, 4 KB
    __shared__ float Es[64*68];             // [q][key] pitch 68, 17 KB

    const float we_h = We[h];
    const size_t kvbase = (size_t)(b*NH + h) * NN * DH;
    const int qrow = q0 + wid*16 + l15;
    const s16x8 qh_f = *(const s16x8*)(Qh + kvbase + (size_t)qrow*DH + hi*8);
    const s16x8 ql_f = *(const s16x8*)(Ql + kvbase + (size_t)qrow*DH + hi*8);

    // staging maps
    const int sk_key = t >> 2, sk_ch = t & 3;
    const int ks_dst = (sk_key*4 + (sk_ch ^ ((sk_key >> 3) & 3))) * 8;
    const size_t ksrc = kvbase + (size_t)sk_key*DH + sk_ch*8;
    const int sv_dh = t >> 3, sv_kg = t & 7;
    const int vs_dst = (sv_kg*32 + (sv_dh ^ (sv_kg & 3))) * 8;
    const size_t vsrc = kvbase + (size_t)sv_dh*NN + sv_kg*8;
    const int se_q = t >> 2, se_seg = t & 3;
    const size_t esrc = ((size_t)b << 20) + (size_t)(q0 + se_q)*NN + se_seg*16;
    const int edst = se_q*68 + se_seg*16;

    // fragment addresses
    const int rbase = 8*(l15 >> 2) + (l15 & 3);     // sigma row part
    const int kxor = hi ^ (l15 >> 2);
    const int eq68 = (wid*16 + l15) * 68;
    const int vxl = l15 ^ hi;                        // dh-swizzle (kg&3 == hi)

    float m_run = -3.0e38f, l_run = 0.f;
    f32x4 O0 = (f32x4){0.f,0.f,0.f,0.f}, O1 = (f32x4){0.f,0.f,0.f,0.f};

    // prefetch tile 0
    uint4 kreg, vreg; float4 ereg[4];
    kreg = *(const uint4*)(Kb + ksrc);
    vreg = *(const uint4*)(Vt + vsrc);
#pragma unroll
    for (int j = 0; j < 4; ++j) ereg[j] = *(const float4*)(Eg + esrc + j*4);

    for (int mt = 0; mt < 16; ++mt) {
        __syncthreads();   // previous tile's readers done
        *(uint4*)&Ks[ks_dst] = kreg;
        *(uint4*)&Vs[vs_dst] = vreg;
#pragma unroll
        for (int j = 0; j < 4; ++j) *(float4*)&Es[edst + j*4] = ereg[j];
        __syncthreads();
        if (mt < 15) {     // prefetch next tile (overlaps compute below)
            const int m1 = (mt + 1) * 64;
            kreg = *(const uint4*)(Kb + ksrc + (size_t)m1*DH);
            vreg = *(const uint4*)(Vt + vsrc + m1);
#pragma unroll
            for (int j = 0; j < 4; ++j) ereg[j] = *(const float4*)(Eg + esrc + m1 + j*4);
        }

        // --- QK^T with sigma permutation: sc[j] <-> key = koff + 8*hi + j
        float s[16];
#pragma unroll
        for (int kt = 0; kt < 4; ++kt) {
            const int koff = 32*(kt & 1) + 4*(kt >> 1);
            const s16x8 kfr = *(const s16x8*)&Ks[((koff + rbase)*4 + kxor) * 8];
            f32x4 sc = (f32x4){0.f,0.f,0.f,0.f};
            sc = __builtin_amdgcn_mfma_f32_16x16x32_bf16(kfr, ql_f, sc, 0,0,0);
            sc = __builtin_amdgcn_mfma_f32_16x16x32_bf16(kfr, qh_f, sc, 0,0,0);
            const float4 e4 = *(const float4*)&Es[eq68 + koff + 8*hi];
            s[kt*4+0] = fmaf(e4.x, we_h, sc[0]);
            s[kt*4+1] = fmaf(e4.y, we_h, sc[1]);
            s[kt*4+2] = fmaf(e4.z, we_h, sc[2]);
            s[kt*4+3] = fmaf(e4.w, we_h, sc[3]);
        }

        // --- online softmax (lane q = l15), defer-max THR=8
        float tm = s[0];
#pragma unroll
        for (int i = 1; i < 16; ++i) tm = fmaxf(tm, s[i]);
        tm = fmaxf(tm, __shfl_xor(tm, 16));
        tm = fmaxf(tm, __shfl_xor(tm, 32));
        if (!__all(tm <= m_run + 8.0f)) {
            const float mn = fmaxf(m_run, tm);
            const float alpha = __expf(m_run - mn);
            m_run = mn;
            l_run *= alpha;
            const float a0 = __shfl(alpha, hi4+0);
            const float a1 = __shfl(alpha, hi4+1);
            const float a2 = __shfl(alpha, hi4+2);
            const float a3 = __shfl(alpha, hi4+3);
            O0[0]*=a0; O0[1]*=a1; O0[2]*=a2; O0[3]*=a3;
            O1[0]*=a0; O1[1]*=a1; O1[2]*=a2; O1[3]*=a3;
        }
        float ps = 0.f;
#pragma unroll
        for (int i = 0; i < 16; ++i) { s[i] = __expf(s[i] - m_run); ps += s[i]; }
        ps += __shfl_xor(ps, 16);
        ps += __shfl_xor(ps, 32);
        l_run += ps;

        // pack P in-lane (sigma makes QK^T regs == PV A-frag layout)
        union { s16x8 v; unsigned int u[4]; } pf0, pf1;
        pf0.u[0] = packbf(s[0],  s[1]);   pf0.u[1] = packbf(s[2],  s[3]);
        pf0.u[2] = packbf(s[8],  s[9]);   pf0.u[3] = packbf(s[10], s[11]);
        pf1.u[0] = packbf(s[4],  s[5]);   pf1.u[1] = packbf(s[6],  s[7]);
        pf1.u[2] = packbf(s[12], s[13]);  pf1.u[3] = packbf(s[14], s[15]);

        // --- PV from swizzled Vs
        {
            const s16x8 v00 = *(const s16x8*)&Vs[((0*4+hi)*32 + vxl) * 8];
            const s16x8 v01 = *(const s16x8*)&Vs[((0*4+hi)*32 + 16 + vxl) * 8];
            O0 = __builtin_amdgcn_mfma_f32_16x16x32_bf16(pf0.v, v00, O0, 0,0,0);
            O1 = __builtin_amdgcn_mfma_f32_16x16x32_bf16(pf0.v, v01, O1, 0,0,0);
            const s16x8 v10 = *(const s16x8*)&Vs[((4+hi)*32 + vxl) * 8];
            const s16x8 v11 = *(const s16x8*)&Vs[((4+hi)*32 + 16 + vxl) * 8];
            O0 = __builtin_amdgcn_mfma_f32_16x16x32_bf16(pf1.v, v10, O0, 0,0,0);
            O1 = __builtin_amdgcn_mfma_f32_16x16x32_bf16(pf1.v, v11, O1, 0,0,0);
        }
    }

    // epilogue: normalize, split hi/lo, write AO (B,N,H*DH)
    float linv[4];
#pragma unroll
    for (int r = 0; r < 4; ++r) linv[r] = 1.0f / __shfl(l_run, hi4 + r);
#pragma unroll
    for (int r = 0; r < 4; ++r) {
        const size_t node = (size_t)b*NN + q0 + wid*16 + hi4 + r;
        {
            const float o = O0[r] * linv[r];
            const unsigned short hb = f2bf(o);
            const size_t idx = node*DOUT + h*DH + l15;
            AOh[idx] = hb; AOl[idx] = f2bf(o - bf2f(hb));
        }
        {
            const float o = O1[r] * linv[r];
            const unsigned short hb = f2bf(o);
            const size_t idx = node*DOUT + h*DH + 16 + l15;
            AOh[idx] = hb; AOl[idx] = f2bf(o - bf2f(hb));
        }
    }
}

// ---------------------------------------------------------------------------
// Kernel 4: out projection (MFMA, staged) + bias + residual + LayerNorm fused.
// Block = 32 nodes x all 256 feats, 512 threads (8 waves x 32 feats).
// LN: per-wave partial sums -> LDS -> cross-wave reduce -> normalize -> d_out.
// ---------------------------------------------------------------------------
__global__ __launch_bounds__(512) void oproj_ln_kernel(
    const unsigned short* __restrict__ AOh, const unsigned short* __restrict__ AOl,
    const unsigned short* __restrict__ Wt,
    const float* __restrict__ bo, const float* __restrict__ X0,
    const float* __restrict__ gam, const float* __restrict__ bet,
    float* __restrict__ out)
{
    const int N0 = blockIdx.x * 32;
    const int t = threadIdx.x, lane = t & 63, wid = t >> 6;
    const int l15 = lane & 15, hi = lane >> 4, hi4 = hi * 4;

    __shared__ unsigned short Ball[64*4*8];    // 4 KB
    __shared__ unsigned short Aall[512*4*8];   // 32 KB
    __shared__ float LNs[8][2][16], LNq[8][2][16];

    // B staging (threads < 256)
    const int brow = t >> 2, bkg = t & 3;
    const int bnode = brow & 31, bhl = brow >> 5;
    const unsigned short* bsrcp = bhl ? AOl : AOh;
    const size_t bsrc = (size_t)(N0 + bnode)*256 + bkg*8;
    const int bdst = (brow*4 + (bkg ^ ((bnode >> 3) & 3))) * 8;

    // A staging (Wo = mat 3), 4 chunks per thread
    int adst[4]; size_t asrc[4];
#pragma unroll
    for (int i = 0; i < 4; ++i) {
        const int c = t + 512*i, row = c >> 2, kgrp = c & 3;
        const int hl = row >> 8, feat = row & 255;
        asrc[i] = (size_t)3*131072 + (size_t)hl*65536 + (size_t)feat*256 + kgrp*8;
        adst[i] = (row*4 + (kgrp ^ ((feat >> 3) & 3))) * 8;
    }

    // fragment addresses
    int aaddr[2][2], baddr[2][2];
#pragma unroll
    for (int rt = 0; rt < 2; ++rt) {
        const int feat = wid*32 + rt*16 + l15;
        const int ax = hi ^ ((feat >> 3) & 3);
        aaddr[rt][0] = (feat*4 + ax) * 8;
        aaddr[rt][1] = ((256 + feat)*4 + ax) * 8;
    }
#pragma unroll
    for (int c = 0; c < 2; ++c) {
        const int node = c*16 + l15;
        const int bx = hi ^ ((node >> 3) & 3);
        baddr[c][0] = (node*4 + bx) * 8;
        baddr[c][1] = ((32 + node)*4 + bx) * 8;
    }

    f32x4 acc[2][2];
#pragma unroll
    for (int rt = 0; rt < 2; ++rt)
#pragma unroll
        for (int c = 0; c < 2; ++c) acc[rt][c] = (f32x4){0.f,0.f,0.f,0.f};

    // prefetch k-tile 0
    uint4 breg, areg[4];
    if (t < 256) breg = *(const uint4*)(bsrcp + bsrc);
#pragma unroll
    for (int i = 0; i < 4; ++i) areg[i] = *(const uint4*)(Wt + asrc[i]);

    for (int ks = 0; ks < 8; ++ks) {
        __syncthreads();
        if (t < 256) *(uint4*)&Ball[bdst] = breg;
#pragma unroll
        for (int i = 0; i < 4; ++i) *(uint4*)&Aall[adst[i]] = areg[i];
        __syncthreads();
        if (ks < 7) {
            const int k0 = (ks + 1) * 32;
            if (t < 256) breg = *(const uint4*)(bsrcp + bsrc + k0);
#pragma unroll
            for (int i = 0; i < 4; ++i) areg[i] = *(const uint4*)(Wt + asrc[i] + k0);
        }
        s16x8 ah[2], al[2], bh[2], bl[2];
#pragma unroll
        for (int rt = 0; rt < 2; ++rt) {
            ah[rt] = *(const s16x8*)&Aall[aaddr[rt][0]];
            al[rt] = *(const s16x8*)&Aall[aaddr[rt][1]];
        }
#pragma unroll
        for (int c = 0; c < 2; ++c) {
            bh[c] = *(const s16x8*)&Ball[baddr[c][0]];
            bl[c] = *(const s16x8*)&Ball[baddr[c][1]];
        }
#pragma unroll
        for (int rt = 0; rt < 2; ++rt)
#pragma unroll
            for (int c = 0; c < 2; ++c) {
                acc[rt][c] = __builtin_amdgcn_mfma_f32_16x16x32_bf16(ah[rt], bh[c], acc[rt][c], 0,0,0);
                acc[rt][c] = __builtin_amdgcn_mfma_f32_16x16x32_bf16(al[rt], bh[c], acc[rt][c], 0,0,0);
                acc[rt][c] = __builtin_amdgcn_mfma_f32_16x16x32_bf16(ah[rt], bl[c], acc[rt][c], 0,0,0);
            }
    }

    // --- epilogue: x = proj + bias + residual, then fused LayerNorm ---
    float x[2][2][4];
    float sm[2] = {0.f, 0.f}, sq[2] = {0.f, 0.f};
#pragma unroll
    for (int rt = 0; rt < 2; ++rt) {
        const int f0 = wid*32 + rt*16 + hi4;
        const float4 bs4 = *(const float4*)&bo[f0];
        const float bsa[4] = {bs4.x, bs4.y, bs4.z, bs4.w};
#pragma unroll
        for (int c = 0; c < 2; ++c) {
            const size_t g = N0 + c*16 + l15;
            const float4 r4 = *(const float4*)&X0[g*256 + f0];
            const float ra[4] = {r4.x, r4.y, r4.z, r4.w};
#pragma unroll
            for (int r = 0; r < 4; ++r) {
                const float v = acc[rt][c][r] + bsa[r] + ra[r];
                x[rt][c][r] = v;
                sm[c] += v;
                sq[c] += v * v;
            }
        }
    }
#pragma unroll
    for (int c = 0; c < 2; ++c) {
        sm[c] += __shfl_xor(sm[c], 16);
        sm[c] += __shfl_xor(sm[c], 32);
        sq[c] += __shfl_xor(sq[c], 16);
        sq[c] += __shfl_xor(sq[c], 32);
    }
    if (hi == 0) {
#pragma unroll
        for (int c = 0; c < 2; ++c) { LNs[wid][c][l15] = sm[c]; LNq[wid][c][l15] = sq[c]; }
    }
    __syncthreads();
#pragma unroll
    for (int c = 0; c < 2; ++c) {
        float S = 0.f, Q = 0.f;
#pragma unroll
        for (int w = 0; w < 8; ++w) { S += LNs[w][c][l15]; Q += LNq[w][c][l15]; }
        const float mu = S * (1.0f / 256.0f);
        const float var = Q * (1.0f / 256.0f) - mu*mu;
        const float rs = rsqrtf(var + LN_EPS);
        const size_t g = N0 + c*16 + l15;
#pragma unroll
        for (int rt = 0; rt < 2; ++rt) {
            const int f0 = wid*32 + rt*16 + hi4;
            const float4 g4 = *(const float4*)&gam[f0];
            const float4 b4 = *(const float4*)&bet[f0];
            float4 o;
            o.x = (x[rt][c][0] - mu) * rs * g4.x + b4.x;
            o.y = (x[rt][c][1] - mu) * rs * g4.y + b4.y;
            o.z = (x[rt][c][2] - mu) * rs * g4.z + b4.z;
            o.w = (x[rt][c][3] - mu) * rs * g4.w + b4.w;
            *(float4*)&out[g*256 + f0] = o;
        }
    }
}

// ---------------------------------------------------------------------------
extern "C" void kernel_launch(void* const* d_in, const int* in_sizes, int n_in,
                              void* d_out, int out_size, void* d_ws, size_t ws_size,
                              hipStream_t stream) {
    const float* X    = (const float*)d_in[0];
    const float* E    = (const float*)d_in[1];
    const float* Wq   = (const float*)d_in[2];
    const float* bq   = (const float*)d_in[3];
    const float* Wk   = (const float*)d_in[4];
    const float* bk   = (const float*)d_in[5];
    const float* Wv   = (const float*)d_in[6];
    const float* bv   = (const float*)d_in[7];
    const float* We   = (const float*)d_in[8];
    // d_in[9] = be: constant over softmax axis -> cancels exactly; dropped
    const float* Wo   = (const float*)d_in[10];
    const float* bo   = (const float*)d_in[11];
    const float* gam  = (const float*)d_in[12];
    const float* bet  = (const float*)d_in[13];
    float* out = (float*)d_out;

    // workspace (shorts), ~26 MB:
    // [Wt 4x(64K hi + 64K lo)][Qh][Ql][Kb][Vt][AOh][AOl]
    const size_t TENS = (size_t)NB * NN * DOUT;   // 2,097,152
    unsigned short* SH = (unsigned short*)d_ws;
    unsigned short* Wt  = SH;
    unsigned short* Qh  = SH + 524288;
    unsigned short* Ql  = Qh + TENS;
    unsigned short* Kb  = Ql + TENS;
    unsigned short* Vt  = Kb + TENS;
    unsigned short* AOh = Vt + TENS;
    unsigned short* AOl = AOh + TENS;

    wsplit_kernel<<<dim3(4,4,4), 256, 0, stream>>>(Wq, Wk, Wv, Wo, Wt);
    qkv_kernel<<<dim3(128,4), 256, 0, stream>>>(X, Wt, bq, bk, bv, Qh, Ql, Kb, Vt);
    attn_kernel<<<NB*NH*(NN/64), 256, 0, stream>>>(Qh, Ql, Kb, Vt, E, We, AOh, AOl);
    oproj_ln_kernel<<<256, 512, 0, stream>>>(AOh, AOl, Wt, bo, X, gam, bet, out);
}

// Round 5
// 170.932 us; speedup vs baseline: 1.6250x; 1.6250x over previous
//
#include <hip/hip_runtime.h>

// Problem constants (fixed by setup_inputs)
#define NB   8      // batch
#define NN   1024   // nodes
#define DIN  256
#define DOUT 256
#define NH   8      // heads
#define DH   32     // head dim
constexpr float LN_EPS   = 1e-5f;
constexpr float QK_SCALE = 0.17677669529663687f; // 1/sqrt(32)

typedef __attribute__((ext_vector_type(8))) short s16x8;   // 8 bf16 (4 VGPR)
typedef __attribute__((ext_vector_type(4))) float f32x4;   // MFMA acc

__device__ __forceinline__ unsigned short f2bf(float f) {  // RNE fp32->bf16
    unsigned int u = __float_as_uint(f);
    u += 0x7FFFu + ((u >> 16) & 1u);
    return (unsigned short)(u >> 16);
}
__device__ __forceinline__ float bf2f(unsigned short h) {
    return __uint_as_float(((unsigned int)h) << 16);
}
__device__ __forceinline__ unsigned int packbf(float a, float b) {
    return (unsigned int)f2bf(a) | ((unsigned int)f2bf(b) << 16);
}

// async global->LDS, 16B per lane.  LDS dest = wave-uniform base + lane*16.
__device__ __forceinline__ void gl16(const void* g, void* l) {
    __builtin_amdgcn_global_load_lds(
        (__attribute__((address_space(1))) void*)g,
        (__attribute__((address_space(3))) void*)l, 16, 0, 0);
}

// ---------------------------------------------------------------------------
// Kernel 1: weight convert -> pre-swizzled gload_lds stream images.
//   qimg: [F0blk(4)][ks(8)][1536 blocks] for Wq/Wk/Wv (row = hl*192+mat*64+feat)
//   oimg: [ks(8)][2048 blocks] for Wo      (row = hl*256+feat)
// block swizzle (both): i = row*4+kgrp; phys = i ^ ((i>>3)&3)   (involution)
// ---------------------------------------------------------------------------
__global__ __launch_bounds__(256) void wsplit_kernel(
    const float* __restrict__ W0, const float* __restrict__ W1,
    const float* __restrict__ W2, const float* __restrict__ W3,
    unsigned short* __restrict__ qimg, unsigned short* __restrict__ oimg)
{
    const int mat = blockIdx.z;
    const int k0 = blockIdx.x * 64, n0 = blockIdx.y * 64;
    const float* W = (mat==0)?W0:(mat==1)?W1:(mat==2)?W2:W3;
    __shared__ float T[64][65];
    const int t = threadIdx.x;
    {
        const int r = t >> 2, cs = (t & 3) * 16;
        const float* src = W + (size_t)(k0 + r)*256 + n0 + cs;
#pragma unroll
        for (int i = 0; i < 4; ++i) {
            float4 v = *(const float4*)(src + i*4);
            T[r][cs+i*4+0] = v.x; T[r][cs+i*4+1] = v.y;
            T[r][cs+i*4+2] = v.z; T[r][cs+i*4+3] = v.w;
        }
    }
    __syncthreads();
#pragma unroll
    for (int idx = 0; idx < 4; ++idx) {
        const int u = t + 256*idx;            // 0..1023
        const int feat = u & 63, ck = (u>>6)&7, hl = u>>9;
        unsigned short buf[8];
#pragma unroll
        for (int e = 0; e < 8; ++e) {
            const float x = T[ck*8 + e][feat];
            const unsigned short hb = f2bf(x);
            buf[e] = hl ? f2bf(x - bf2f(hb)) : hb;
        }
        const int ksg = (k0>>5) + (ck>>2);
        const int kgrp = ck & 3;
        if (mat < 3) {
            const int row = hl*192 + mat*64 + feat;
            int i = row*4 + kgrp; i ^= ((i>>3)&3);
            *(s16x8*)(qimg + ((size_t)((n0>>6)*8 + ksg)*1536 + i)*8) = *(const s16x8*)buf;
        } else {
            const int row = hl*256 + n0 + feat;
            int i = row*4 + kgrp; i ^= ((i>>3)&3);
            *(s16x8*)(oimg + ((size_t)ksg*2048 + i)*8) = *(const s16x8*)buf;
        }
    }
}

// ---------------------------------------------------------------------------
// Kernel 2: QKV via MFMA.  W staged by pure gload_lds from qimg (linear);
// X converted fp32->hi/lo during staging (reg roundtrip only for X: 8 floats).
// Double-buffered LDS, ONE barrier per k-step.
// Block = 64 nodes x 64 feats(all 3 mats), 256 thr.
// ---------------------------------------------------------------------------
__global__ __launch_bounds__(256) void qkv_kernel(
    const float* __restrict__ X, const unsigned short* __restrict__ qimg,
    const float* __restrict__ bq, const float* __restrict__ bk, const float* __restrict__ bv,
    unsigned short* __restrict__ Qh, unsigned short* __restrict__ Ql,
    unsigned short* __restrict__ Kb, unsigned short* __restrict__ Vt)
{
    __shared__ __align__(16) char lds[65536];  // [W0 24K][W1 24K][X0 8K][X1 8K]
    const int N0 = blockIdx.x * 64;
    const int F0blk = blockIdx.y;
    const int t = threadIdx.x, lane = t & 63, wid = t >> 6;
    const int l15 = lane & 15, hi = lane >> 4, hi4 = hi * 4;

    const unsigned short* wsrc0 = qimg + ((size_t)(F0blk*8)*1536 + wid*384 + lane)*8;
    const int xnode = t >> 2, xkc = t & 3;
    const float* xsrc0 = X + (size_t)(N0 + xnode)*256 + xkc*8;
    int ixh = xnode*4 + xkc;        ixh ^= ((ixh>>3)&3);
    int ixl = (64 + xnode)*4 + xkc; ixl ^= ((ixl>>3)&3);

    int aoff[3][2], boff[4][2];
#pragma unroll
    for (int m = 0; m < 3; ++m)
#pragma unroll
        for (int hl = 0; hl < 2; ++hl) {
            int row = hl*192 + m*64 + wid*16 + l15;
            int i = row*4 + hi; i ^= ((i>>3)&3);
            aoff[m][hl] = i*16;
        }
#pragma unroll
    for (int c = 0; c < 4; ++c)
#pragma unroll
        for (int hl = 0; hl < 2; ++hl) {
            int row = hl*64 + c*16 + l15;
            int i = row*4 + hi; i ^= ((i>>3)&3);
            boff[c][hl] = i*16;
        }

    // prologue: stage k-step 0 into buffers 0
#pragma unroll
    for (int i = 0; i < 6; ++i)
        gl16(wsrc0 + i*512, lds + wid*6144 + i*1024);
    {
        float4 a = *(const float4*)(xsrc0);
        float4 b = *(const float4*)(xsrc0 + 4);
        const float v[8] = {a.x,a.y,a.z,a.w,b.x,b.y,b.z,b.w};
        unsigned short h8[8], l8[8];
#pragma unroll
        for (int j = 0; j < 8; ++j) { h8[j] = f2bf(v[j]); l8[j] = f2bf(v[j] - bf2f(h8[j])); }
        *(s16x8*)(lds + 49152 + ixh*16) = *(const s16x8*)h8;
        *(s16x8*)(lds + 49152 + ixl*16) = *(const s16x8*)l8;
    }
    __syncthreads();

    f32x4 acc[3][4];
#pragma unroll
    for (int m = 0; m < 3; ++m)
#pragma unroll
        for (int c = 0; c < 4; ++c) acc[m][c] = (f32x4){0.f,0.f,0.f,0.f};

    for (int ks = 0; ks < 8; ++ks) {
        const int wb  = (ks&1)*24576,        xb  = 49152 + (ks&1)*8192;
        const int wbn = ((ks+1)&1)*24576,    xbn = 49152 + ((ks+1)&1)*8192;
        float4 xa, xc;
        if (ks < 7) {
#pragma unroll
            for (int i = 0; i < 6; ++i)
                gl16(wsrc0 + (size_t)(ks+1)*12288 + i*512, lds + wbn + wid*6144 + i*1024);
            xa = *(const float4*)(xsrc0 + (ks+1)*32);
            xc = *(const float4*)(xsrc0 + (ks+1)*32 + 4);
        }
        s16x8 ah[3], al[3];
#pragma unroll
        for (int m = 0; m < 3; ++m) {
            ah[m] = *(const s16x8*)(lds + wb + aoff[m][0]);
            al[m] = *(const s16x8*)(lds + wb + aoff[m][1]);
        }
#pragma unroll
        for (int c = 0; c < 4; ++c) {
            const s16x8 bh = *(const s16x8*)(lds + xb + boff[c][0]);
            const s16x8 bl = *(const s16x8*)(lds + xb + boff[c][1]);
#pragma unroll
            for (int m = 0; m < 3; ++m) {
                acc[m][c] = __builtin_amdgcn_mfma_f32_16x16x32_bf16(ah[m], bh, acc[m][c], 0,0,0);
                acc[m][c] = __builtin_amdgcn_mfma_f32_16x16x32_bf16(al[m], bh, acc[m][c], 0,0,0);
                acc[m][c] = __builtin_amdgcn_mfma_f32_16x16x32_bf16(ah[m], bl, acc[m][c], 0,0,0);
            }
        }
        if (ks < 7) {
            const float v[8] = {xa.x,xa.y,xa.z,xa.w,xc.x,xc.y,xc.z,xc.w};
            unsigned short h8[8], l8[8];
#pragma unroll
            for (int j = 0; j < 8; ++j) { h8[j] = f2bf(v[j]); l8[j] = f2bf(v[j] - bf2f(h8[j])); }
            *(s16x8*)(lds + xbn + ixh*16) = *(const s16x8*)h8;
            *(s16x8*)(lds + xbn + ixl*16) = *(const s16x8*)l8;
        }
        __syncthreads();
    }

    // epilogue (layouts proven in rounds 3/4)
    const int f0 = F0blk*64 + wid*16 + hi4;
    const int hh = f0 >> 5, d0 = f0 & 31;
#pragma unroll
    for (int m = 0; m < 3; ++m) {
        const float* bias = (m==0) ? bq : (m==1) ? bk : bv;
        const float4 bs4 = *(const float4*)&bias[f0];
        const float bsa[4] = {bs4.x, bs4.y, bs4.z, bs4.w};
#pragma unroll
        for (int c = 0; c < 4; ++c) {
            const int g = N0 + c*16 + l15;
            const int b = g >> 10, nn = g & (NN - 1);
            const size_t base = ((size_t)(b*NH + hh)*NN + nn)*DH + d0;
            if (m == 0) {
                ushort4 qh4, ql4;
#pragma unroll
                for (int r = 0; r < 4; ++r) {
                    const float q = (acc[0][c][r] + bsa[r]) * QK_SCALE;
                    const unsigned short hb = f2bf(q);
                    ((unsigned short*)&qh4)[r] = hb;
                    ((unsigned short*)&ql4)[r] = f2bf(q - bf2f(hb));
                }
                *(ushort4*)&Qh[base] = qh4;
                *(ushort4*)&Ql[base] = ql4;
            } else if (m == 1) {
                ushort4 kb4;
#pragma unroll
                for (int r = 0; r < 4; ++r)
                    ((unsigned short*)&kb4)[r] = f2bf(acc[1][c][r] + bsa[r]);
                *(ushort4*)&Kb[base] = kb4;
            } else {
#pragma unroll
                for (int r = 0; r < 4; ++r)
                    Vt[((size_t)(b*NH + hh)*DH + d0 + r)*NN + nn] =
                        f2bf(acc[2][c][r] + bsa[r]);
            }
        }
    }
}

// ---------------------------------------------------------------------------
// Kernel 3: flash attention.  gload_lds double-buffered K/V/E (pre-swizzled
// sources, involution maps; all ds_read_b128 groups bank-balanced), sigma
// key-permutation (P stays in registers), defer-max.  ONE barrier per tile.
// Epilogue writes AO directly in oproj's pre-swizzled stream image.
// ---------------------------------------------------------------------------
__global__ __launch_bounds__(256) void attn_kernel(
    const unsigned short* __restrict__ Qh, const unsigned short* __restrict__ Ql,
    const unsigned short* __restrict__ Kb, const unsigned short* __restrict__ Vt,
    const float* __restrict__ Eg, const float* __restrict__ We,
    unsigned short* __restrict__ AOimg)
{
    __shared__ __align__(16) char lds[49152];  // 2 x [K 4K][V 4K][E 16K]
    const int bid = blockIdx.x;
    const int b = bid & 7, h = (bid >> 3) & 7, qt = bid >> 6;
    const int q0 = qt * 64;
    const int t = threadIdx.x, lane = t & 63, wid = t >> 6;
    const int l15 = lane & 15, hi = lane >> 4, hi4 = hi * 4;

    const float we_h = We[h];
    const size_t kvbase = (size_t)(b*NH + h) * NN * DH;
    const int qrow = q0 + wid*16 + l15;
    const s16x8 qh_f = *(const s16x8*)(Qh + kvbase + (size_t)qrow*DH + hi*8);
    const s16x8 ql_f = *(const s16x8*)(Ql + kvbase + (size_t)qrow*DH + hi*8);

    // --- per-lane pre-swizzled staging sources (tile 0) ---
    const int jk = t;
    const int ik = jk ^ ((jk>>3)&1) ^ (((jk>>5)&1)<<1);
    const unsigned short* ksrc = Kb + kvbase + (size_t)(ik>>2)*DH + (ik&3)*8;
    const int iv = jk ^ ((jk>>3)&7);
    const unsigned short* vsrc = Vt + kvbase + (size_t)(iv>>3)*NN + (iv&7)*8;
    const float* esrc[4];
#pragma unroll
    for (int k = 0; k < 4; ++k) {
        const int je = wid*256 + k*64 + lane;
        const int ie = je ^ ((je>>4)&7);
        esrc[k] = Eg + ((size_t)b<<20) + (size_t)(q0 + (ie>>4))*NN + (ie&15)*4;
    }
    char* kdst = lds + wid*1024;
    char* vdst = lds + 4096 + wid*1024;
    char* edst = lds + 8192 + wid*4096;

    // --- read byte-offsets (within buffer) ---
    const int rbase = 8*(l15 >> 2) + (l15 & 3);   // sigma row part
    int koffB[4], eoffB[4], voffB[4];
#pragma unroll
    for (int kt = 0; kt < 4; ++kt) {
        const int ko = 32*(kt&1) + 4*(kt>>1);
        int i = (ko + rbase)*4 + hi;
        i = i ^ ((i>>3)&1) ^ (((i>>5)&1)<<1);
        koffB[kt] = i*16;
        int ie = (wid*16 + l15)*16 + (ko>>2) + 2*hi;
        ie = ie ^ ((ie>>4)&7);
        eoffB[kt] = 8192 + ie*16;
    }
#pragma unroll
    for (int c = 0; c < 4; ++c) {       // c = (half<<1) | (d>=16)
        const int d = (c&1)*16 + l15;
        int i = d*8 + (c>>1)*4 + hi;
        i = i ^ ((i>>3)&7);
        voffB[c] = 4096 + i*16;
    }

    // prologue: stage tile 0 into buffer 0
    gl16(ksrc, kdst);
    gl16(vsrc, vdst);
#pragma unroll
    for (int k = 0; k < 4; ++k) gl16(esrc[k], edst + k*1024);
    __syncthreads();

    float m_run = -3.0e38f, l_run = 0.f;
    f32x4 O0 = (f32x4){0.f,0.f,0.f,0.f}, O1 = (f32x4){0.f,0.f,0.f,0.f};

    for (int mt = 0; mt < 16; ++mt) {
        const int bb = (mt&1)*24576;
        const int nb = 24576 - bb;
        if (mt < 15) {   // issue next tile's loads (in flight through compute)
            const int m1 = (mt+1)*64;
            gl16(ksrc + (size_t)m1*DH, kdst + nb);
            gl16(vsrc + m1, vdst + nb);
#pragma unroll
            for (int k = 0; k < 4; ++k) gl16(esrc[k] + m1, edst + nb + k*1024);
        }

        // QK^T (sigma): s[kt*4+j] <-> key = koff + 8*hi + j
        float s[16];
#pragma unroll
        for (int kt = 0; kt < 4; ++kt) {
            const s16x8 kfr = *(const s16x8*)(lds + bb + koffB[kt]);
            f32x4 sc = (f32x4){0.f,0.f,0.f,0.f};
            sc = __builtin_amdgcn_mfma_f32_16x16x32_bf16(kfr, ql_f, sc, 0,0,0);
            sc = __builtin_amdgcn_mfma_f32_16x16x32_bf16(kfr, qh_f, sc, 0,0,0);
            const float4 e4 = *(const float4*)(lds + bb + eoffB[kt]);
            s[kt*4+0] = fmaf(e4.x, we_h, sc[0]);
            s[kt*4+1] = fmaf(e4.y, we_h, sc[1]);
            s[kt*4+2] = fmaf(e4.z, we_h, sc[2]);
            s[kt*4+3] = fmaf(e4.w, we_h, sc[3]);
        }

        // online softmax (lane q = l15), defer-max THR=8
        float tm = s[0];
#pragma unroll
        for (int i = 1; i < 16; ++i) tm = fmaxf(tm, s[i]);
        tm = fmaxf(tm, __shfl_xor(tm, 16));
        tm = fmaxf(tm, __shfl_xor(tm, 32));
        if (!__all(tm <= m_run + 8.0f)) {
            const float mn = fmaxf(m_run, tm);
            const float alpha = __expf(m_run - mn);
            m_run = mn;
            l_run *= alpha;
            const float a0 = __shfl(alpha, hi4+0);
            const float a1 = __shfl(alpha, hi4+1);
            const float a2 = __shfl(alpha, hi4+2);
            const float a3 = __shfl(alpha, hi4+3);
            O0[0]*=a0; O0[1]*=a1; O0[2]*=a2; O0[3]*=a3;
            O1[0]*=a0; O1[1]*=a1; O1[2]*=a2; O1[3]*=a3;
        }
        float ps = 0.f;
#pragma unroll
        for (int i = 0; i < 16; ++i) { s[i] = __expf(s[i] - m_run); ps += s[i]; }
        ps += __shfl_xor(ps, 16);
        ps += __shfl_xor(ps, 32);
        l_run += ps;

        // pack P in-lane (sigma => QK^T regs are exactly PV A-frags)
        union { s16x8 v; unsigned int u[4]; } pf0, pf1;
        pf0.u[0] = packbf(s[0],  s[1]);   pf0.u[1] = packbf(s[2],  s[3]);
        pf0.u[2] = packbf(s[8],  s[9]);   pf0.u[3] = packbf(s[10], s[11]);
        pf1.u[0] = packbf(s[4],  s[5]);   pf1.u[1] = packbf(s[6],  s[7]);
        pf1.u[2] = packbf(s[12], s[13]);  pf1.u[3] = packbf(s[14], s[15]);

        // PV
        {
            const s16x8 v00 = *(const s16x8*)(lds + bb + voffB[0]);
            const s16x8 v01 = *(const s16x8*)(lds + bb + voffB[1]);
            O0 = __builtin_amdgcn_mfma_f32_16x16x32_bf16(pf0.v, v00, O0, 0,0,0);
            O1 = __builtin_amdgcn_mfma_f32_16x16x32_bf16(pf0.v, v01, O1, 0,0,0);
            const s16x8 v10 = *(const s16x8*)(lds + bb + voffB[2]);
            const s16x8 v11 = *(const s16x8*)(lds + bb + voffB[3]);
            O0 = __builtin_amdgcn_mfma_f32_16x16x32_bf16(pf1.v, v10, O0, 0,0,0);
            O1 = __builtin_amdgcn_mfma_f32_16x16x32_bf16(pf1.v, v11, O1, 0,0,0);
        }
        __syncthreads();   // drains gload_lds (vmcnt0) + ds ops for ALL waves
    }

    // epilogue: normalize, write into oproj's pre-swizzled AO image
    float linv[4];
#pragma unroll
    for (int r = 0; r < 4; ++r) linv[r] = 1.0f / __shfl(l_run, hi4 + r);
#pragma unroll
    for (int r = 0; r < 4; ++r) {
        const int gnode = b*NN + q0 + wid*16 + hi4 + r;
        const int nblk = gnode >> 4, nrow = gnode & 15;
        const size_t base = (size_t)(nblk*8 + h) * 128;
        const int elem = l15 & 7;
        {   // dims l15 (dt=0)
            const float o = O0[r] * linv[r];
            const unsigned short hb = f2bf(o);
            const unsigned short lb = f2bf(o - bf2f(hb));
            const int kgrp = l15 >> 3;
            int i0 = nrow*4 + kgrp;        i0 ^= ((i0>>3)&3);
            int i1 = (16+nrow)*4 + kgrp;   i1 ^= ((i1>>3)&3);
            AOimg[(base + i0)*8 + elem] = hb;
            AOimg[(base + i1)*8 + elem] = lb;
        }
        {   // dims 16+l15 (dt=1)
            const float o = O1[r] * linv[r];
            const unsigned short hb = f2bf(o);
            const unsigned short lb = f2bf(o - bf2f(hb));
            const int kgrp = 2 + (l15 >> 3);
            int i0 = nrow*4 + kgrp;        i0 ^= ((i0>>3)&3);
            int i1 = (16+nrow)*4 + kgrp;   i1 ^= ((i1>>3)&3);
            AOimg[(base + i0)*8 + elem] = hb;
            AOimg[(base + i1)*8 + elem] = lb;
        }
    }
}

// ---------------------------------------------------------------------------
// Kernel 4: out projection + bias + residual + LayerNorm.  A (Wo image) and
// B (AO image) both staged by pure linear gload_lds; dbuf; 1 barrier/k-step.
// Block = 16 nodes x 256 feats, 512 thr (8 waves x 32 feats).
// ---------------------------------------------------------------------------
__global__ __launch_bounds__(512) void oproj_ln_kernel(
    const unsigned short* __restrict__ AOimg, const unsigned short* __restrict__ oimg,
    const float* __restrict__ bo, const float* __restrict__ X0,
    const float* __restrict__ gam, const float* __restrict__ bet,
    float* __restrict__ out)
{
    __shared__ __align__(16) char lds[69632];  // [A0 32K][A1 32K][B0 2K][B1 2K]
    __shared__ float LNs[8][16], LNq[8][16];
    const int nblk = blockIdx.x;
    const int N0 = nblk * 16;
    const int t = threadIdx.x, lane = t & 63, wid = t >> 6;
    const int l15 = lane & 15, hi = lane >> 4, hi4 = hi * 4;

    const unsigned short* asrc0 = oimg + ((size_t)wid*256 + lane)*8;            // +ks*16384
    const unsigned short* bsrc0 = AOimg + ((size_t)(nblk*8)*128 + wid*64 + lane)*8; // +ks*1024

    int aoff[2][2], boffr[2];
#pragma unroll
    for (int rt = 0; rt < 2; ++rt)
#pragma unroll
        for (int hl = 0; hl < 2; ++hl) {
            int row = hl*256 + wid*32 + rt*16 + l15;
            int i = row*4 + hi; i ^= ((i>>3)&3);
            aoff[rt][hl] = i*16;
        }
#pragma unroll
    for (int hl = 0; hl < 2; ++hl) {
        int row = hl*16 + l15;
        int i = row*4 + hi; i ^= ((i>>3)&3);
        boffr[hl] = 65536 + i*16;
    }

    // prologue: stage k-step 0
#pragma unroll
    for (int i = 0; i < 4; ++i)
        gl16(asrc0 + i*512, lds + wid*4096 + i*1024);
    if (wid < 2) gl16(bsrc0, lds + 65536 + wid*1024);
    __syncthreads();

    f32x4 acc[2];
    acc[0] = (f32x4){0.f,0.f,0.f,0.f};
    acc[1] = (f32x4){0.f,0.f,0.f,0.f};

    for (int ks = 0; ks < 8; ++ks) {
        const int ab = (ks&1)*32768, bbx = (ks&1)*2048;
        if (ks < 7) {
            const int abn = 32768 - ab, bbn = 2048 - bbx;
#pragma unroll
            for (int i = 0; i < 4; ++i)
                gl16(asrc0 + (size_t)(ks+1)*16384 + i*512, lds + abn + wid*4096 + i*1024);
            if (wid < 2) gl16(bsrc0 + (size_t)(ks+1)*1024, lds + 65536 + (bbn - 2048) + wid*1024 + 2048);
        }
        const s16x8 bh = *(const s16x8*)(lds + bbx + boffr[0]);
        const s16x8 bl = *(const s16x8*)(lds + bbx + boffr[1]);
#pragma unroll
        for (int rt = 0; rt < 2; ++rt) {
            const s16x8 ah = *(const s16x8*)(lds + ab + aoff[rt][0]);
            const s16x8 al = *(const s16x8*)(lds + ab + aoff[rt][1]);
            acc[rt] = __builtin_amdgcn_mfma_f32_16x16x32_bf16(ah, bh, acc[rt], 0,0,0);
            acc[rt] = __builtin_amdgcn_mfma_f32_16x16x32_bf16(al, bh, acc[rt], 0,0,0);
            acc[rt] = __builtin_amdgcn_mfma_f32_16x16x32_bf16(ah, bl, acc[rt], 0,0,0);
        }
        __syncthreads();
    }

    // epilogue: x = proj + bias + residual, fused LayerNorm
    float x[2][4];
    float sm = 0.f, sq = 0.f;
#pragma unroll
    for (int rt = 0; rt < 2; ++rt) {
        const int f0 = wid*32 + rt*16 + hi4;
        const float4 bs4 = *(const float4*)&bo[f0];
        const float4 r4  = *(const float4*)&X0[(size_t)(N0 + l15)*256 + f0];
        const float bsa[4] = {bs4.x, bs4.y, bs4.z, bs4.w};
        const float ra[4]  = {r4.x, r4.y, r4.z, r4.w};
#pragma unroll
        for (int r = 0; r < 4; ++r) {
            const float v = acc[rt][r] + bsa[r] + ra[r];
            x[rt][r] = v;
            sm += v;
            sq += v * v;
        }
    }
    sm += __shfl_xor(sm, 16); sm += __shfl_xor(sm, 32);
    sq += __shfl_xor(sq, 16); sq += __shfl_xor(sq, 32);
    if (hi == 0) { LNs[wid][l15] = sm; LNq[wid][l15] = sq; }
    __syncthreads();
    float S = 0.f, Q = 0.f;
#pragma unroll
    for (int w = 0; w < 8; ++w) { S += LNs[w][l15]; Q += LNq[w][l15]; }
    const float mu = S * (1.0f / 256.0f);
    const float var = Q * (1.0f / 256.0f) - mu*mu;
    const float rs = rsqrtf(var + LN_EPS);
#pragma unroll
    for (int rt = 0; rt < 2; ++rt) {
        const int f0 = wid*32 + rt*16 + hi4;
        const float4 g4 = *(const float4*)&gam[f0];
        const float4 b4 = *(const float4*)&bet[f0];
        float4 o;
        o.x = (x[rt][0] - mu) * rs * g4.x + b4.x;
        o.y = (x[rt][1] - mu) * rs * g4.y + b4.y;
        o.z = (x[rt][2] - mu) * rs * g4.z + b4.z;
        o.w = (x[rt][3] - mu) * rs * g4.w + b4.w;
        *(float4*)&out[(size_t)(N0 + l15)*256 + f0] = o;
    }
}

// ---------------------------------------------------------------------------
extern "C" void kernel_launch(void* const* d_in, const int* in_sizes, int n_in,
                              void* d_out, int out_size, void* d_ws, size_t ws_size,
                              hipStream_t stream) {
    const float* X    = (const float*)d_in[0];
    const float* E    = (const float*)d_in[1];
    const float* Wq   = (const float*)d_in[2];
    const float* bq   = (const float*)d_in[3];
    const float* Wk   = (const float*)d_in[4];
    const float* bk   = (const float*)d_in[5];
    const float* Wv   = (const float*)d_in[6];
    const float* bv   = (const float*)d_in[7];
    const float* We   = (const float*)d_in[8];
    // d_in[9] = be: constant over softmax axis -> cancels exactly; dropped
    const float* Wo   = (const float*)d_in[10];
    const float* bo   = (const float*)d_in[11];
    const float* gam  = (const float*)d_in[12];
    const float* bet  = (const float*)d_in[13];
    float* out = (float*)d_out;

    // workspace (shorts), ~26 MB:
    // [qimg 393216][oimg 131072][Qh][Ql][Kb][Vt (2M each)][AOimg 4M]
    const size_t TENS = (size_t)NB * NN * DOUT;   // 2,097,152
    unsigned short* SH = (unsigned short*)d_ws;
    unsigned short* qimg  = SH;
    unsigned short* oimg  = qimg + 393216;
    unsigned short* Qh    = oimg + 131072;
    unsigned short* Ql    = Qh + TENS;
    unsigned short* Kb    = Ql + TENS;
    unsigned short* Vt    = Kb + TENS;
    unsigned short* AOimg = Vt + TENS;

    wsplit_kernel<<<dim3(4,4,4), 256, 0, stream>>>(Wq, Wk, Wv, Wo, qimg, oimg);
    qkv_kernel<<<dim3(128,4), 256, 0, stream>>>(X, qimg, bq, bk, bv, Qh, Ql, Kb, Vt);
    attn_kernel<<<NB*NH*(NN/64), 256, 0, stream>>>(Qh, Ql, Kb, Vt, E, We, AOimg);
    oproj_ln_kernel<<<512, 512, 0, stream>>>(AOimg, oimg, bo, X, gam, bet, out);
}